// Round 1
// baseline (389.651 us; speedup 1.0000x reference)
//
#include <hip/hip_runtime.h>

// RandCropResize: B=64, C=3, H=W=512, fp32.
// Per batch b: crop img[b, :, y1:y2, x1:x2] and bilinear-resize (align_corners
// =False) back to (H, W). Memory-bound: 201 MB write + ~crop-region reads.
//
// Mapping: 1 block per output row (b,c,oy); 256 threads x 2 px = 512 px.
// y interpolation coords are uniform per block; x coords computed per pixel.
// Stores vectorized as float2; gather reads are near-contiguous (monotone
// source-x indices) so L1/L2 coalesce them.

#define BB 64
#define CC 3
#define HH 512
#define WW 512

__global__ __launch_bounds__(256) void rand_crop_resize_kernel(
    const float* __restrict__ img,
    const int* __restrict__ y1a, const int* __restrict__ y2a,
    const int* __restrict__ x1a, const int* __restrict__ x2a,
    float* __restrict__ out)
{
    const int row = blockIdx.x;            // 0 .. B*C*H-1, = (b*C + c)*H + oy
    const int oy  = row & (HH - 1);
    const int bc  = row >> 9;              // / 512
    const int c   = bc % CC;
    const int b   = bc / CC;

    const int Y1 = y1a[b], Y2 = y2a[b], X1 = x1a[b], X2 = x2a[b];

    // ---- y-axis source coords (uniform across the block) ----
    // Reference: s = (i + 0.5) * n / out - 0.5; clip [0, n-1]; i0=floor(s);
    // i1 = min(i0+1, n-1); w = s - i0.  (/512 is an exact pow2 scale.)
    const int   ny_i = Y2 - Y1;
    const float ny   = (float)ny_i;
    float sy = ((float)oy + 0.5f) * ny * (1.0f / 512.0f) - 0.5f;
    sy = fminf(fmaxf(sy, 0.0f), ny - 1.0f);
    int iy0 = (int)floorf(sy);
    int iy1 = min(iy0 + 1, ny_i - 1);
    const float wy = sy - (float)iy0;
    iy0 += Y1;
    iy1 += Y1;

    const size_t plane = ((size_t)(b * CC + c)) * (size_t)HH;
    const float* __restrict__ row0 = img + (plane + (size_t)iy0) * (size_t)WW;
    const float* __restrict__ row1 = img + (plane + (size_t)iy1) * (size_t)WW;

    const int   nx_i  = X2 - X1;
    const float nx    = (float)nx_i;
    const int   nxm1  = nx_i - 1;
    const float nxm1f = nx - 1.0f;

    const int t = threadIdx.x;
    float2 res;

    #pragma unroll
    for (int k = 0; k < 2; ++k) {
        const int ox = 2 * t + k;
        float sx = ((float)ox + 0.5f) * nx * (1.0f / 512.0f) - 0.5f;
        sx = fminf(fmaxf(sx, 0.0f), nxm1f);
        int ix0 = (int)floorf(sx);
        int ix1 = min(ix0 + 1, nxm1);
        const float wx = sx - (float)ix0;
        ix0 += X1;
        ix1 += X1;

        const float v00 = row0[ix0];
        const float v01 = row0[ix1];
        const float v10 = row1[ix0];
        const float v11 = row1[ix1];

        // Match reference assoc: rows = r0 + (r1-r0)*wy; out = c0 + (c1-c0)*wx
        const float r0 = v00 + (v10 - v00) * wy;
        const float r1 = v01 + (v11 - v01) * wy;
        const float v  = r0 + (r1 - r0) * wx;
        if (k == 0) res.x = v; else res.y = v;
    }

    float2* __restrict__ orow = (float2*)(out + (size_t)row * (size_t)WW);
    orow[t] = res;
}

extern "C" void kernel_launch(void* const* d_in, const int* in_sizes, int n_in,
                              void* d_out, int out_size, void* d_ws, size_t ws_size,
                              hipStream_t stream) {
    const float* img = (const float*)d_in[0];
    const int*   y1  = (const int*)d_in[1];
    const int*   y2  = (const int*)d_in[2];
    const int*   x1  = (const int*)d_in[3];
    const int*   x2  = (const int*)d_in[4];
    float*       out = (float*)d_out;

    dim3 grid(BB * CC * HH);   // 98304 blocks, one per output row
    dim3 block(256);           // 2 px / thread, float2 stores
    hipLaunchKernelGGL(rand_crop_resize_kernel, grid, block, 0, stream,
                       img, y1, y2, x1, x2, out);
}

// Round 2
// 354.305 us; speedup vs baseline: 1.0998x; 1.0998x over previous
//
#include <hip/hip_runtime.h>

// RandCropResize v2: LDS row-staging + XCD swizzle.
// B=64, C=3, H=W=512, fp32. One block per output row (b,c,oy).
// Stage the 2 bilinear source rows (full 512 floats each, always 16B-aligned,
// never OOB) into LDS with one float4 load per thread, then gather from LDS.
// XCD swizzle: blockIdx round-robins over 8 XCDs; remap so each XCD owns a
// contiguous 8-batch slice of rows -> L2 locality, no cross-XCD re-fetch.

#define BB 64
#define CC 3
#define HH 512
#define WW 512
#define NROWS (BB * CC * HH)       // 98304
#define ROWS_PER_XCD (NROWS / 8)   // 12288

__global__ __launch_bounds__(256) void rand_crop_resize_kernel(
    const float* __restrict__ img,
    const int* __restrict__ y1a, const int* __restrict__ y2a,
    const int* __restrict__ x1a, const int* __restrict__ x2a,
    float* __restrict__ out)
{
    __shared__ float s0[WW];
    __shared__ float s1[WW];

    // XCD-aware swizzle: physical block i -> XCD i%8 (heuristic). Give XCD k
    // the contiguous logical rows [k*12288, (k+1)*12288) = 8 whole batches.
    const int row = (blockIdx.x & 7) * ROWS_PER_XCD + (blockIdx.x >> 3);

    const int oy  = row & (HH - 1);
    const int bc  = row >> 9;              // (b*C + c)
    const int b   = bc / CC;

    const int Y1 = y1a[b], Y2 = y2a[b], X1 = x1a[b], X2 = x2a[b];

    // ---- y-axis source coords (uniform across the block) ----
    const int   ny_i = Y2 - Y1;
    float sy = ((float)oy + 0.5f) * (float)ny_i * (1.0f / 512.0f) - 0.5f;
    sy = fminf(fmaxf(sy, 0.0f), (float)ny_i - 1.0f);
    int iy0 = (int)floorf(sy);
    int iy1 = min(iy0 + 1, ny_i - 1);
    const float wy = sy - (float)iy0;
    iy0 += Y1;
    iy1 += Y1;

    const size_t plane = (size_t)bc * (size_t)(HH * WW);
    const float* __restrict__ row0 = img + plane + (size_t)iy0 * (size_t)WW;
    const float* __restrict__ row1 = img + plane + (size_t)iy1 * (size_t)WW;

    // ---- stage both source rows into LDS (coalesced float4, aligned) ----
    const int t = threadIdx.x;
    if (t < 128) {
        ((float4*)s0)[t] = ((const float4*)row0)[t];
    } else {
        ((float4*)s1)[t - 128] = ((const float4*)row1)[t - 128];
    }
    __syncthreads();

    // ---- x-axis bilinear from LDS, 2 px/thread, float2 store ----
    const int   nx_i  = X2 - X1;
    const float nx    = (float)nx_i;
    const int   nxm1  = nx_i - 1;
    const float nxm1f = nx - 1.0f;

    float2 res;
    #pragma unroll
    for (int k = 0; k < 2; ++k) {
        const int ox = 2 * t + k;
        float sx = ((float)ox + 0.5f) * nx * (1.0f / 512.0f) - 0.5f;
        sx = fminf(fmaxf(sx, 0.0f), nxm1f);
        int ix0 = (int)floorf(sx);
        int ix1 = min(ix0 + 1, nxm1);
        const float wx = sx - (float)ix0;
        ix0 += X1;
        ix1 += X1;

        const float v00 = s0[ix0];
        const float v01 = s0[ix1];
        const float v10 = s1[ix0];
        const float v11 = s1[ix1];

        const float r0 = v00 + (v10 - v00) * wy;
        const float r1 = v01 + (v11 - v01) * wy;
        const float v  = r0 + (r1 - r0) * wx;
        if (k == 0) res.x = v; else res.y = v;
    }

    float2* __restrict__ orow = (float2*)(out + (size_t)row * (size_t)WW);
    orow[t] = res;
}

extern "C" void kernel_launch(void* const* d_in, const int* in_sizes, int n_in,
                              void* d_out, int out_size, void* d_ws, size_t ws_size,
                              hipStream_t stream) {
    const float* img = (const float*)d_in[0];
    const int*   y1  = (const int*)d_in[1];
    const int*   y2  = (const int*)d_in[2];
    const int*   x1  = (const int*)d_in[3];
    const int*   x2  = (const int*)d_in[4];
    float*       out = (float*)d_out;

    dim3 grid(NROWS);    // 98304 blocks, one per output row
    dim3 block(256);
    hipLaunchKernelGGL(rand_crop_resize_kernel, grid, block, 0, stream,
                       img, y1, y2, x1, x2, out);
}

// Round 3
// 321.734 us; speedup vs baseline: 1.2111x; 1.1012x over previous
//
#include <hip/hip_runtime.h>

// RandCropResize v3: channel-fused blocks + ds_read2 LDS gathers.
// B=64, C=3, H=W=512, fp32. One block per (b, oy): stages the 6 bilinear
// source rows (2 y-taps x 3 channels, full 512 floats, float4-coalesced)
// into LDS, computes x-coords ONCE, and emits 3 output rows.
// x-gathers read s[ix] and s[ix+1] unconditionally (-> ds_read2_b32); the
// clamp case has wx==0 exactly, and LDS element [512] is zeroed so the dead
// read is finite.

#define BB 64
#define CC 3
#define HH 512
#define WW 512
#define NB (BB * HH)          // 32768 blocks
#define PITCH 516             // floats per LDS row: 512 + pad; 516*4 % 16 == 0

__global__ __launch_bounds__(256) void rand_crop_resize_kernel(
    const float* __restrict__ img,
    const int* __restrict__ y1a, const int* __restrict__ y2a,
    const int* __restrict__ x1a, const int* __restrict__ x2a,
    float* __restrict__ out)
{
    __shared__ float s[6 * PITCH];   // rows: [c*2 + tap]

    // XCD swizzle: give XCD k a contiguous slice of 8 batches.
    const int r  = (blockIdx.x & 7) * (NB / 8) + (blockIdx.x >> 3);
    const int oy = r & (HH - 1);
    const int b  = r >> 9;

    const int Y1 = y1a[b], Y2 = y2a[b], X1 = x1a[b], X2 = x2a[b];

    // ---- y coords (uniform) ----
    const int ny_i = Y2 - Y1;
    float sy = ((float)oy + 0.5f) * (float)ny_i * (1.0f / 512.0f) - 0.5f;
    sy = fminf(fmaxf(sy, 0.0f), (float)ny_i - 1.0f);
    int iy0 = (int)sy;                       // sy >= 0, trunc == floor
    const int iy1 = min(iy0 + 1, ny_i - 1) + Y1;
    const float wy = sy - (float)iy0;
    iy0 += Y1;

    const int t = threadIdx.x;

    // zero the pad element [512] of each LDS row (read when ix0+1 == 512,
    // always multiplied by wx == 0, but must be finite)
    if (t < 6) s[t * PITCH + 512] = 0.0f;

    // ---- stage 6 rows: j in [0,768) float4 chunks; row = j>>7, lane = j&127
    const size_t base = (size_t)b * (size_t)(CC * HH * WW);
    #pragma unroll
    for (int i = 0; i < 3; ++i) {
        const int j    = t + 256 * i;
        const int rw   = j >> 7;             // 0..5
        const int lane = j & 127;
        const int c    = rw >> 1;
        const int iy   = (rw & 1) ? iy1 : iy0;
        const float4 v = ((const float4*)(img + base
                             + (size_t)(c * HH + iy) * (size_t)WW))[lane];
        ((float4*)(s + rw * PITCH))[lane] = v;
    }
    __syncthreads();

    // ---- x bilinear: 2 px/thread, coords shared across 3 channels ----
    const int   nx_i  = X2 - X1;
    const float nx    = (float)nx_i;
    const float nxm1f = nx - 1.0f;

    float2 res[3];
    #pragma unroll
    for (int k = 0; k < 2; ++k) {
        const int ox = 2 * t + k;
        float sx = ((float)ox + 0.5f) * nx * (1.0f / 512.0f) - 0.5f;
        sx = fminf(fmaxf(sx, 0.0f), nxm1f);
        const int   ix0 = (int)sx;           // sx >= 0, trunc == floor
        const float wx  = sx - (float)ix0;
        const int   ix  = X1 + ix0;          // ix+1 <= 512 (pad element)

        #pragma unroll
        for (int c = 0; c < 3; ++c) {
            const float* s0 = s + (2 * c) * PITCH;
            const float* s1 = s0 + PITCH;
            const float v00 = s0[ix];
            const float v01 = s0[ix + 1];    // fuses into ds_read2_b32
            const float v10 = s1[ix];
            const float v11 = s1[ix + 1];
            const float r0 = v00 + (v10 - v00) * wy;
            const float r1 = v01 + (v11 - v01) * wy;
            const float v  = r0 + (r1 - r0) * wx;
            if (k == 0) res[c].x = v; else res[c].y = v;
        }
    }

    #pragma unroll
    for (int c = 0; c < 3; ++c) {
        float2* orow = (float2*)(out
            + ((size_t)(b * CC + c) * (size_t)HH + (size_t)oy) * (size_t)WW);
        orow[t] = res[c];
    }
}

extern "C" void kernel_launch(void* const* d_in, const int* in_sizes, int n_in,
                              void* d_out, int out_size, void* d_ws, size_t ws_size,
                              hipStream_t stream) {
    const float* img = (const float*)d_in[0];
    const int*   y1  = (const int*)d_in[1];
    const int*   y2  = (const int*)d_in[2];
    const int*   x1  = (const int*)d_in[3];
    const int*   x2  = (const int*)d_in[4];
    float*       out = (float*)d_out;

    dim3 grid(NB);      // 32768 blocks, one per (b, oy)
    dim3 block(256);
    hipLaunchKernelGGL(rand_crop_resize_kernel, grid, block, 0, stream,
                       img, y1, y2, x1, x2, out);
}